// Round 5
// baseline (1317.819 us; speedup 1.0000x reference)
//
#include <hip/hip_runtime.h>

#define NN 100000
#define EE 1600000
#define BB 256
#define IN_F 7
#define HH 128

// ---------------- CSR build ----------------

__global__ void count_deg(const int* __restrict__ ei, int* __restrict__ deg, int e) {
    int i = blockIdx.x * 256 + threadIdx.x;
    if (i < e) atomicAdd(&deg[ei[e + i]], 1);   // dst = ei[E + i]
}

__global__ void scan_partial(const int* __restrict__ deg, int* __restrict__ bsum, int n) {
    __shared__ int sd[256];
    int b = blockIdx.x, t = threadIdx.x;
    int base = b * 1024 + t * 4;
    int s = 0;
    #pragma unroll
    for (int k = 0; k < 4; ++k) { int i = base + k; if (i < n) s += deg[i]; }
    sd[t] = s; __syncthreads();
    for (int off = 128; off > 0; off >>= 1) {
        if (t < off) sd[t] += sd[t + off];
        __syncthreads();
    }
    if (t == 0) bsum[b] = sd[0];
}

__global__ void scan_bsum(int* __restrict__ bsum, int nb) {
    __shared__ int sd[256];
    int t = threadIdx.x;
    int v = (t < nb) ? bsum[t] : 0;
    sd[t] = v; __syncthreads();
    for (int off = 1; off < 256; off <<= 1) {
        int add = (t >= off) ? sd[t - off] : 0;
        __syncthreads();
        sd[t] += add;
        __syncthreads();
    }
    if (t < nb) bsum[t] = sd[t] - v;   // exclusive
}

__global__ void scan_apply(const int* __restrict__ deg, const int* __restrict__ bsum,
                           int* __restrict__ rowptr, int* __restrict__ cursor, int n, int e) {
    __shared__ int sd[256];
    int b = blockIdx.x, t = threadIdx.x;
    int base = b * 1024 + t * 4;
    int v[4]; int s = 0;
    #pragma unroll
    for (int k = 0; k < 4; ++k) { int i = base + k; v[k] = (i < n) ? deg[i] : 0; s += v[k]; }
    sd[t] = s; __syncthreads();
    int mine = s;
    for (int off = 1; off < 256; off <<= 1) {
        int add = (t >= off) ? sd[t - off] : 0;
        __syncthreads();
        sd[t] += add;
        __syncthreads();
    }
    int run = sd[t] - mine + bsum[b];
    #pragma unroll
    for (int k = 0; k < 4; ++k) {
        int i = base + k;
        if (i < n) { rowptr[i] = run; cursor[i] = run; }
        run += v[k];
    }
    if (b == 0 && t == 0) rowptr[n] = e;
}

__global__ void fill_csr(const int* __restrict__ ei, int* __restrict__ cursor,
                         int* __restrict__ colarr, int e) {
    int i = blockIdx.x * 256 + threadIdx.x;
    if (i < e) {
        int d = ei[e + i];
        int pos = atomicAdd(&cursor[d], 1);
        colarr[pos] = ei[i];   // src
    }
}

// ---------------- aggregation ----------------

__global__ __launch_bounds__(256) void agg7(const float* __restrict__ xin,
        const int* __restrict__ rowptr, const int* __restrict__ colarr,
        float* __restrict__ h0, int n) {
    int node = blockIdx.x * 32 + (threadIdx.x >> 3);
    int f = threadIdx.x & 7;
    if (node >= n) return;
    int fidx = (f < 7) ? f : 0;
    float acc = xin[node * 7 + fidx];
    int beg = rowptr[node], end = rowptr[node + 1];
    int j = beg;
    for (; j + 4 <= end; j += 4) {
        int s0 = colarr[j], s1 = colarr[j+1], s2 = colarr[j+2], s3 = colarr[j+3];
        float v0 = xin[s0*7 + fidx], v1 = xin[s1*7 + fidx];
        float v2 = xin[s2*7 + fidx], v3 = xin[s3*7 + fidx];
        acc += (v0 + v1) + (v2 + v3);
    }
    for (; j < end; ++j) acc += xin[colarr[j]*7 + fidx];
    h0[node * 8 + f] = (f < 7) ? acc : 0.f;
}

__global__ __launch_bounds__(256) void agg128(const float* __restrict__ xin,
        const int* __restrict__ rowptr, const int* __restrict__ colarr,
        float* __restrict__ hout, int n) {
    int node = blockIdx.x * 2 + (threadIdx.x >> 7);
    int t = threadIdx.x & 127;
    if (node >= n) return;
    float acc = xin[node * 128 + t];
    int beg = rowptr[node], end = rowptr[node + 1];
    int j = beg;
    for (; j + 4 <= end; j += 4) {
        int s0 = colarr[j], s1 = colarr[j+1], s2 = colarr[j+2], s3 = colarr[j+3];
        float v0 = xin[s0*128 + t], v1 = xin[s1*128 + t];
        float v2 = xin[s2*128 + t], v3 = xin[s3*128 + t];
        acc += (v0 + v1) + (v2 + v3);
    }
    for (; j < end; ++j) acc += xin[colarr[j]*128 + t];
    hout[node * 128 + t] = acc;
}

// ---------------- small first linear ----------------

__global__ __launch_bounds__(256) void lin7(const float* __restrict__ h0,
        const float* __restrict__ W, const float* __restrict__ bias,
        float* __restrict__ out, int n) {
    __shared__ float wl[7][128];
    __shared__ float hl[8][8];
    int t = threadIdx.x;
    for (int l = t; l < 7 * 128; l += 256) wl[l >> 7][l & 127] = W[l];
    int row0 = blockIdx.x * 8;
    if (t < 64) {
        int r = t >> 3, k = t & 7;
        int gr = row0 + r;
        hl[r][k] = (gr < n) ? h0[gr * 8 + k] : 0.f;
    }
    __syncthreads();
    int c = t & 127, g = t >> 7;
    float bv = bias[c];
    #pragma unroll
    for (int i = 0; i < 4; ++i) {
        int r = g * 4 + i, gr = row0 + r;
        if (gr < n) {
            float acc = bv;
            #pragma unroll
            for (int k = 0; k < 7; ++k) acc += hl[r][k] * wl[k][c];
            out[gr * 128 + c] = fmaxf(acc, 0.f);
        }
    }
}

// ---------------- fused MLP + JK + pool (128 threads, 8x8 microtile, pipelined) ----

// XOR swizzle: logical col c of row r lives at physical col c ^ swz(r).
__device__ __forceinline__ int swz(int r) { return ((r >> 2) & 7) * 4; }

__device__ __forceinline__ void load_a(const float (&a_lds)[64][128], int r0, int kk,
                                       float4 (&buf)[8]) {
    #pragma unroll
    for (int i = 0; i < 8; ++i)
        buf[i] = *(const float4*)&a_lds[r0 + i][kk ^ swz(r0 + i)];
}

__device__ __forceinline__ void load_w(const float* __restrict__ Wp, int kk,
                                       float4 (&buf)[8]) {
    #pragma unroll
    for (int dk = 0; dk < 4; ++dk) {
        buf[2*dk]   = *(const float4*)&Wp[(kk + dk) * 128];
        buf[2*dk+1] = *(const float4*)&Wp[(kk + dk) * 128 + 4];
    }
}

__device__ __forceinline__ void fma4(const float4 (&af)[8], const float4 (&wf)[8],
                                     float (&acc)[8][8]) {
    #pragma unroll
    for (int dk = 0; dk < 4; ++dk) {
        float4 w0 = wf[2*dk], w1 = wf[2*dk+1];
        #pragma unroll
        for (int i = 0; i < 8; ++i) {
            float av = (dk == 0) ? af[i].x : (dk == 1) ? af[i].y
                     : (dk == 2) ? af[i].z : af[i].w;
            acc[i][0] += av * w0.x; acc[i][1] += av * w0.y;
            acc[i][2] += av * w0.z; acc[i][3] += av * w0.w;
            acc[i][4] += av * w1.x; acc[i][5] += av * w1.y;
            acc[i][6] += av * w1.z; acc[i][7] += av * w1.w;
        }
    }
}

// acc[8][8] = a_lds(64x128, swizzled) @ W(128x128, global/L1-L2).
// Register ping-pong double-buffer on both operands: loads for block k+4 are in
// flight while FMAs for block k execute (512 VALU-cyc of cover per load set).
__device__ __forceinline__ void gemm_core_g(const float* __restrict__ W,
        const float (&a_lds)[64][128], int tx, int ty, float (&acc)[8][8])
{
    #pragma unroll
    for (int i = 0; i < 8; ++i)
        #pragma unroll
        for (int j = 0; j < 8; ++j) acc[i][j] = 0.f;
    const float* Wp = W + tx * 8;
    const int r0 = ty * 8;

    float4 afA[8], wfA[8], afB[8], wfB[8];
    load_a(a_lds, r0, 0, afA); load_w(Wp, 0, wfA);
    for (int kk = 0; kk < 128; kk += 8) {
        load_a(a_lds, r0, kk + 4, afB); load_w(Wp, kk + 4, wfB);
        fma4(afA, wfA, acc);
        if (kk + 8 < 128) { load_a(a_lds, r0, kk + 8, afA); load_w(Wp, kk + 8, wfA); }
        fma4(afB, wfB, acc);
    }
}

// Per layer: [t = relu(in@Wa+ba)] ; x = relu(t@Wb+bb) ; y = x@Wjk(+bjk) ; pooled += y
template<bool DO_A, bool LASTB, bool WRITE_X>
__global__ __launch_bounds__(128) void mlp_fused(
        const float* __restrict__ in,
        const float* __restrict__ Wa, const float* __restrict__ ba,
        const float* __restrict__ Wb, const float* __restrict__ bb,
        const float* __restrict__ Wjk, const float* __restrict__ bjk,
        const int* __restrict__ batch,
        float* __restrict__ xout, float* __restrict__ pooled, int n)
{
    __shared__ float a_lds[64][128];   // 32 KB -> 5 blocks/CU by LDS
    int t = threadIdx.x, tx = t & 15, ty = t >> 4;   // tx 0..15, ty 0..7
    int row0 = blockIdx.x * 64;
    int c0 = tx * 8, r0 = ty * 8;
    float acc[8][8];

    // stage input rows (zero-fill invalid rows), swizzled
    #pragma unroll
    for (int it = 0; it < 16; ++it) {
        int l = t + 128 * it;
        int r = l >> 5, c4 = (l & 31) * 4;
        int gr = row0 + r;
        float4 av = make_float4(0.f, 0.f, 0.f, 0.f);
        if (gr < n) av = *(const float4*)&in[gr * 128 + c4];
        *(float4*)&a_lds[r][c4 ^ swz(r)] = av;
    }
    __syncthreads();

    if (DO_A) {
        gemm_core_g(Wa, a_lds, tx, ty, acc);
        __syncthreads();   // all a_lds reads done
        float bv[8];
        #pragma unroll
        for (int j = 0; j < 8; ++j) bv[j] = ba[c0 + j];
        #pragma unroll
        for (int i = 0; i < 8; ++i) {
            int r = r0 + i, gr = row0 + r;
            float o[8];
            #pragma unroll
            for (int j = 0; j < 8; ++j)
                o[j] = (gr < n) ? fmaxf(acc[i][j] + bv[j], 0.f) : 0.f;
            int s = swz(r);
            *(float4*)&a_lds[r][c0 ^ s]       = make_float4(o[0], o[1], o[2], o[3]);
            *(float4*)&a_lds[r][(c0 + 4) ^ s] = make_float4(o[4], o[5], o[6], o[7]);
        }
        __syncthreads();
    }

    gemm_core_g(Wb, a_lds, tx, ty, acc);
    __syncthreads();
    {
        float bv[8];
        #pragma unroll
        for (int j = 0; j < 8; ++j) bv[j] = bb[c0 + j];
        #pragma unroll
        for (int i = 0; i < 8; ++i) {
            int r = r0 + i, gr = row0 + r;
            float o[8];
            #pragma unroll
            for (int j = 0; j < 8; ++j)
                o[j] = (gr < n) ? fmaxf(acc[i][j] + bv[j], 0.f) : 0.f;
            int s = swz(r);
            *(float4*)&a_lds[r][c0 ^ s]       = make_float4(o[0], o[1], o[2], o[3]);
            *(float4*)&a_lds[r][(c0 + 4) ^ s] = make_float4(o[4], o[5], o[6], o[7]);
            if (WRITE_X && gr < n) {
                *(float4*)&xout[gr * 128 + c0]     = make_float4(o[0], o[1], o[2], o[3]);
                *(float4*)&xout[gr * 128 + c0 + 4] = make_float4(o[4], o[5], o[6], o[7]);
            }
        }
    }
    __syncthreads();

    gemm_core_g(Wjk, a_lds, tx, ty, acc);
    __syncthreads();   // a_lds now free for reduction scratch

    if (LASTB) {
        float bv[8];
        #pragma unroll
        for (int j = 0; j < 8; ++j) bv[j] = bjk[c0 + j];
        #pragma unroll
        for (int i = 0; i < 8; ++i) {
            int gr = row0 + r0 + i;
            if (gr < n) {
                #pragma unroll
                for (int j = 0; j < 8; ++j) acc[i][j] += bv[j];
            }
        }
    }

    int row_last = row0 + 63; if (row_last > n - 1) row_last = n - 1;
    int g_first = batch[row0];
    int g_last  = batch[row_last];
    float* red = &a_lds[0][0];   // 1024 floats scratch
    if (g_first == g_last) {
        float s[8];
        #pragma unroll
        for (int j = 0; j < 8; ++j) {
            s[j] = 0.f;
            #pragma unroll
            for (int i = 0; i < 8; ++i) s[j] += acc[i][j];   // invalid rows are exact zeros
        }
        #pragma unroll
        for (int j = 0; j < 8; ++j) red[ty * 128 + c0 + j] = s[j];
        __syncthreads();
        float tot = 0.f;
        #pragma unroll
        for (int g = 0; g < 8; ++g) tot += red[g * 128 + t];
        atomicAdd(&pooled[g_first * 128 + t], tot);
    } else {
        #pragma unroll
        for (int i = 0; i < 8; ++i) {
            int gr = row0 + r0 + i;
            if (gr < n) {
                int g = batch[gr];
                #pragma unroll
                for (int j = 0; j < 8; ++j)
                    atomicAdd(&pooled[g * 128 + c0 + j], acc[i][j]);
            }
        }
    }
}

// ---------------- classifier ----------------

__global__ __launch_bounds__(256) void classifier(const float* __restrict__ pooled,
        const float* __restrict__ Wc1, const float* __restrict__ bc1,
        const float* __restrict__ gamma, const float* __restrict__ beta,
        const float* __restrict__ rmean, const float* __restrict__ rvar,
        const float* __restrict__ Wc2, const float* __restrict__ bc2,
        float* __restrict__ out) {
    int g = blockIdx.x, t = threadIdx.x;
    __shared__ float p[128];
    __shared__ float r0[256], r1[256];
    if (t < 128) p[t] = pooled[g * 128 + t];
    __syncthreads();
    float acc = bc1[t];
    #pragma unroll 8
    for (int k = 0; k < 128; ++k) acc += p[k] * Wc1[k * 256 + t];
    float z = (acc - rmean[t]) * rsqrtf(rvar[t] + 1e-5f) * gamma[t] + beta[t];
    z = fmaxf(z, 0.f);
    r0[t] = z * Wc2[t * 2 + 0];
    r1[t] = z * Wc2[t * 2 + 1];
    __syncthreads();
    for (int s = 128; s > 0; s >>= 1) {
        if (t < s) { r0[t] += r0[t + s]; r1[t] += r1[t + s]; }
        __syncthreads();
    }
    if (t == 0) {
        out[g * 2 + 0] = r0[0] + bc2[0];
        out[g * 2 + 1] = r1[0] + bc2[1];
    }
}

// ---------------- launch ----------------

static inline size_t al256(size_t x) { return (x + 255) & ~size_t(255); }

extern "C" void kernel_launch(void* const* d_in, const int* in_sizes, int n_in,
                              void* d_out, int out_size, void* d_ws, size_t ws_size,
                              hipStream_t stream) {
    const float* x    = (const float*)d_in[0];
    const int*   ei   = (const int*)  d_in[1];
    const int*   batch= (const int*)  d_in[3];
    const float* W0a = (const float*)d_in[4];  const float* b0a = (const float*)d_in[5];
    const float* W0b = (const float*)d_in[6];  const float* b0b = (const float*)d_in[7];
    const float* W1a = (const float*)d_in[8];  const float* b1a = (const float*)d_in[9];
    const float* W1b = (const float*)d_in[10]; const float* b1b = (const float*)d_in[11];
    const float* W2a = (const float*)d_in[12]; const float* b2a = (const float*)d_in[13];
    const float* W2b = (const float*)d_in[14]; const float* b2b = (const float*)d_in[15];
    const float* Wjk = (const float*)d_in[16]; const float* bjk = (const float*)d_in[17];
    const float* Wc1 = (const float*)d_in[18]; const float* bc1 = (const float*)d_in[19];
    const float* gamma=(const float*)d_in[20]; const float* beta= (const float*)d_in[21];
    const float* rmean=(const float*)d_in[22]; const float* rvar= (const float*)d_in[23];
    const float* Wc2 = (const float*)d_in[24]; const float* bc2 = (const float*)d_in[25];
    float* out = (float*)d_out;

    const int N = NN, E = EE, B = BB;

    char* w = (char*)d_ws;
    size_t off = 0;
    int* deg    = (int*)(w + off); off = al256(off + (size_t)N * 4);
    int* rowptr = (int*)(w + off); off = al256(off + (size_t)(N + 1) * 4);
    int* cursor = (int*)(w + off); off = al256(off + (size_t)N * 4);
    int* colarr = (int*)(w + off); off = al256(off + (size_t)E * 4);
    int* bsum   = (int*)(w + off); off = al256(off + 1024 * 4);
    float* h0   = (float*)(w + off); off = al256(off + (size_t)N * 8 * 4);
    float* SA   = (float*)(w + off); off = al256(off + (size_t)N * 128 * 4);
    float* SB   = (float*)(w + off); off = al256(off + (size_t)N * 128 * 4);
    float* XC   = (float*)(w + off); off = al256(off + (size_t)N * 128 * 4);
    float* pooled = (float*)(w + off); off = al256(off + (size_t)B * 128 * 4);

    hipMemsetAsync(deg, 0, (size_t)N * 4, stream);
    hipMemsetAsync(pooled, 0, (size_t)B * 128 * 4, stream);

    int nb = (N + 1023) / 1024;   // 98

    count_deg<<<(E + 255) / 256, 256, 0, stream>>>(ei, deg, E);
    scan_partial<<<nb, 256, 0, stream>>>(deg, bsum, N);
    scan_bsum<<<1, 256, 0, stream>>>(bsum, nb);
    scan_apply<<<nb, 256, 0, stream>>>(deg, bsum, rowptr, cursor, N, E);
    fill_csr<<<(E + 255) / 256, 256, 0, stream>>>(ei, cursor, colarr, E);

    int gLin = (N + 63) / 64;   // 1563

    // Layer 0: agg(d=7) -> lin7 (= t0) -> fused [x1; jk0; pool]
    agg7<<<(N + 31) / 32, 256, 0, stream>>>(x, rowptr, colarr, h0, N);
    lin7<<<(N + 7) / 8, 256, 0, stream>>>(h0, W0a, b0a, SB, N);
    mlp_fused<false, false, true><<<gLin, 128, 0, stream>>>(
        SB, nullptr, nullptr, W0b, b0b, Wjk, nullptr, batch, XC, pooled, N);

    // Layer 1
    agg128<<<(N + 1) / 2, 256, 0, stream>>>(XC, rowptr, colarr, SA, N);
    mlp_fused<true, false, true><<<gLin, 128, 0, stream>>>(
        SA, W1a, b1a, W1b, b1b, Wjk + 128 * 128, nullptr, batch, XC, pooled, N);

    // Layer 2 (x3 never materialized)
    agg128<<<(N + 1) / 2, 256, 0, stream>>>(XC, rowptr, colarr, SA, N);
    mlp_fused<true, true, false><<<gLin, 128, 0, stream>>>(
        SA, W2a, b2a, W2b, b2b, Wjk + 256 * 128, bjk, batch, nullptr, pooled, N);

    classifier<<<B, 256, 0, stream>>>(pooled, Wc1, bc1, gamma, beta,
                                      rmean, rvar, Wc2, bc2, out);
}

// Round 6
// 1187.307 us; speedup vs baseline: 1.1099x; 1.1099x over previous
//
#include <hip/hip_runtime.h>

#define NN 100000
#define EE 1600000
#define BB 256
#define IN_F 7
#define HH 128

// ---------------- CSR build ----------------

__global__ void count_deg(const int* __restrict__ ei, int* __restrict__ deg, int e) {
    int i = blockIdx.x * 256 + threadIdx.x;
    if (i < e) atomicAdd(&deg[ei[e + i]], 1);   // dst = ei[E + i]
}

__global__ void scan_partial(const int* __restrict__ deg, int* __restrict__ bsum, int n) {
    __shared__ int sd[256];
    int b = blockIdx.x, t = threadIdx.x;
    int base = b * 1024 + t * 4;
    int s = 0;
    #pragma unroll
    for (int k = 0; k < 4; ++k) { int i = base + k; if (i < n) s += deg[i]; }
    sd[t] = s; __syncthreads();
    for (int off = 128; off > 0; off >>= 1) {
        if (t < off) sd[t] += sd[t + off];
        __syncthreads();
    }
    if (t == 0) bsum[b] = sd[0];
}

__global__ void scan_bsum(int* __restrict__ bsum, int nb) {
    __shared__ int sd[256];
    int t = threadIdx.x;
    int v = (t < nb) ? bsum[t] : 0;
    sd[t] = v; __syncthreads();
    for (int off = 1; off < 256; off <<= 1) {
        int add = (t >= off) ? sd[t - off] : 0;
        __syncthreads();
        sd[t] += add;
        __syncthreads();
    }
    if (t < nb) bsum[t] = sd[t] - v;   // exclusive
}

__global__ void scan_apply(const int* __restrict__ deg, const int* __restrict__ bsum,
                           int* __restrict__ rowptr, int* __restrict__ cursor, int n, int e) {
    __shared__ int sd[256];
    int b = blockIdx.x, t = threadIdx.x;
    int base = b * 1024 + t * 4;
    int v[4]; int s = 0;
    #pragma unroll
    for (int k = 0; k < 4; ++k) { int i = base + k; v[k] = (i < n) ? deg[i] : 0; s += v[k]; }
    sd[t] = s; __syncthreads();
    int mine = s;
    for (int off = 1; off < 256; off <<= 1) {
        int add = (t >= off) ? sd[t - off] : 0;
        __syncthreads();
        sd[t] += add;
        __syncthreads();
    }
    int run = sd[t] - mine + bsum[b];
    #pragma unroll
    for (int k = 0; k < 4; ++k) {
        int i = base + k;
        if (i < n) { rowptr[i] = run; cursor[i] = run; }
        run += v[k];
    }
    if (b == 0 && t == 0) rowptr[n] = e;
}

__global__ void fill_csr(const int* __restrict__ ei, int* __restrict__ cursor,
                         int* __restrict__ colarr, int e) {
    int i = blockIdx.x * 256 + threadIdx.x;
    if (i < e) {
        int d = ei[e + i];
        int pos = atomicAdd(&cursor[d], 1);
        colarr[pos] = ei[i];   // src
    }
}

// ---------------- layer-0 aggregation (d=7) ----------------

__global__ __launch_bounds__(256) void agg7(const float* __restrict__ xin,
        const int* __restrict__ rowptr, const int* __restrict__ colarr,
        float* __restrict__ h0, int n) {
    int node = blockIdx.x * 32 + (threadIdx.x >> 3);
    int f = threadIdx.x & 7;
    if (node >= n) return;
    int fidx = (f < 7) ? f : 0;
    float acc = xin[node * 7 + fidx];
    int beg = rowptr[node], end = rowptr[node + 1];
    int j = beg;
    for (; j + 4 <= end; j += 4) {
        int s0 = colarr[j], s1 = colarr[j+1], s2 = colarr[j+2], s3 = colarr[j+3];
        float v0 = xin[s0*7 + fidx], v1 = xin[s1*7 + fidx];
        float v2 = xin[s2*7 + fidx], v3 = xin[s3*7 + fidx];
        acc += (v0 + v1) + (v2 + v3);
    }
    for (; j < end; ++j) acc += xin[colarr[j]*7 + fidx];
    h0[node * 8 + f] = (f < 7) ? acc : 0.f;
}

// ---------------- small first linear ----------------

__global__ __launch_bounds__(256) void lin7(const float* __restrict__ h0,
        const float* __restrict__ W, const float* __restrict__ bias,
        float* __restrict__ out, int n) {
    __shared__ float wl[7][128];
    __shared__ float hl[8][8];
    int t = threadIdx.x;
    for (int l = t; l < 7 * 128; l += 256) wl[l >> 7][l & 127] = W[l];
    int row0 = blockIdx.x * 8;
    if (t < 64) {
        int r = t >> 3, k = t & 7;
        int gr = row0 + r;
        hl[r][k] = (gr < n) ? h0[gr * 8 + k] : 0.f;
    }
    __syncthreads();
    int c = t & 127, g = t >> 7;
    float bv = bias[c];
    #pragma unroll
    for (int i = 0; i < 4; ++i) {
        int r = g * 4 + i, gr = row0 + r;
        if (gr < n) {
            float acc = bv;
            #pragma unroll
            for (int k = 0; k < 7; ++k) acc += hl[r][k] * wl[k][c];
            out[gr * 128 + c] = fmaxf(acc, 0.f);
        }
    }
}

// ------- fused [aggregate] + MLP + JK + pool (256 threads, 4x8 microtile) -------

// XOR swizzle: logical col c of row r lives at physical col c ^ swz(r).
__device__ __forceinline__ int swz(int r) { return ((r >> 2) & 7) * 4; }

// acc[4][8] = a_lds(64x128, swizzled) @ W(128x128, global/L1-L2). No dbuf:
// compiler schedules loads (R5 showed explicit dbuf costs VGPR -> occupancy).
__device__ __forceinline__ void gemm_core_g(const float* __restrict__ W,
        const float (&a_lds)[64][128], int tx, int ty, float (&acc)[4][8])
{
    #pragma unroll
    for (int i = 0; i < 4; ++i)
        #pragma unroll
        for (int j = 0; j < 8; ++j) acc[i][j] = 0.f;
    const float* Wp = W + tx * 8;
    const int r0 = ty * 4;
    for (int kk = 0; kk < 128; kk += 4) {
        float4 af[4];
        #pragma unroll
        for (int i = 0; i < 4; ++i)
            af[i] = *(const float4*)&a_lds[r0 + i][kk ^ swz(r0 + i)];
        #pragma unroll
        for (int dk = 0; dk < 4; ++dk) {
            float4 w0 = *(const float4*)&Wp[(kk + dk) * 128];
            float4 w1 = *(const float4*)&Wp[(kk + dk) * 128 + 4];
            #pragma unroll
            for (int i = 0; i < 4; ++i) {
                float av = (dk == 0) ? af[i].x : (dk == 1) ? af[i].y
                         : (dk == 2) ? af[i].z : af[i].w;
                acc[i][0] += av * w0.x; acc[i][1] += av * w0.y;
                acc[i][2] += av * w0.z; acc[i][3] += av * w0.w;
                acc[i][4] += av * w1.x; acc[i][5] += av * w1.y;
                acc[i][6] += av * w1.z; acc[i][7] += av * w1.w;
            }
        }
    }
}

// Per layer: [agg via CSR] ; [t = relu(agg@Wa+ba)] ; x = relu(t@Wb+bb) ;
//            y = x@Wjk(+bjk) ; pooled[batch] += y ; [xout = x]
template<bool GATHER, bool DO_A, bool LASTB, bool WRITE_X>
__global__ __launch_bounds__(256) void mlp_fused(
        const float* __restrict__ in,
        const int* __restrict__ rowptr, const int* __restrict__ colarr,
        const float* __restrict__ Wa, const float* __restrict__ ba,
        const float* __restrict__ Wb, const float* __restrict__ bb,
        const float* __restrict__ Wjk, const float* __restrict__ bjk,
        const int* __restrict__ batch,
        float* __restrict__ xout, float* __restrict__ pooled, int n)
{
    __shared__ float a_lds[64][128];   // 32 KB
    int t = threadIdx.x, tx = t & 15, ty = t >> 4;   // tx 0..15, ty 0..15
    int row0 = blockIdx.x * 64;
    int c0 = tx * 8, r0 = ty * 4;
    float acc[4][8];

    if (GATHER) {
        // aggregation fused into staging: 4 threads per row, each 32 cols
        int r = t >> 2, q = t & 3;
        int gr = row0 + r;
        float4 a[8];
        #pragma unroll
        for (int i = 0; i < 8; ++i) a[i] = make_float4(0.f, 0.f, 0.f, 0.f);
        if (gr < n) {
            const float* xp = &in[(size_t)gr * 128];
            #pragma unroll
            for (int i = 0; i < 8; ++i) a[i] = *(const float4*)&xp[(i * 4 + q) * 4];
            int beg = rowptr[gr], end = rowptr[gr + 1];
            for (int j = beg; j < end; ++j) {
                const float* sp = &in[(size_t)colarr[j] * 128];
                #pragma unroll
                for (int i = 0; i < 8; ++i) {
                    float4 v = *(const float4*)&sp[(i * 4 + q) * 4];
                    a[i].x += v.x; a[i].y += v.y; a[i].z += v.z; a[i].w += v.w;
                }
            }
        }
        int s = swz(r);
        #pragma unroll
        for (int i = 0; i < 8; ++i)
            *(float4*)&a_lds[r][((i * 4 + q) * 4) ^ s] = a[i];
    } else {
        #pragma unroll
        for (int it = 0; it < 8; ++it) {
            int l = t + 256 * it;
            int r = l >> 5, c4 = (l & 31) * 4;
            int gr = row0 + r;
            float4 av = make_float4(0.f, 0.f, 0.f, 0.f);
            if (gr < n) av = *(const float4*)&in[gr * 128 + c4];
            *(float4*)&a_lds[r][c4 ^ swz(r)] = av;
        }
    }
    __syncthreads();

    if (DO_A) {
        gemm_core_g(Wa, a_lds, tx, ty, acc);
        __syncthreads();
        float bv[8];
        #pragma unroll
        for (int j = 0; j < 8; ++j) bv[j] = ba[c0 + j];
        #pragma unroll
        for (int i = 0; i < 4; ++i) {
            int r = r0 + i, gr = row0 + r;
            float o[8];
            #pragma unroll
            for (int j = 0; j < 8; ++j)
                o[j] = (gr < n) ? fmaxf(acc[i][j] + bv[j], 0.f) : 0.f;
            int s = swz(r);
            *(float4*)&a_lds[r][c0 ^ s]       = make_float4(o[0], o[1], o[2], o[3]);
            *(float4*)&a_lds[r][(c0 + 4) ^ s] = make_float4(o[4], o[5], o[6], o[7]);
        }
        __syncthreads();
    }

    gemm_core_g(Wb, a_lds, tx, ty, acc);
    __syncthreads();
    {
        float bv[8];
        #pragma unroll
        for (int j = 0; j < 8; ++j) bv[j] = bb[c0 + j];
        #pragma unroll
        for (int i = 0; i < 4; ++i) {
            int r = r0 + i, gr = row0 + r;
            float o[8];
            #pragma unroll
            for (int j = 0; j < 8; ++j)
                o[j] = (gr < n) ? fmaxf(acc[i][j] + bv[j], 0.f) : 0.f;
            int s = swz(r);
            *(float4*)&a_lds[r][c0 ^ s]       = make_float4(o[0], o[1], o[2], o[3]);
            *(float4*)&a_lds[r][(c0 + 4) ^ s] = make_float4(o[4], o[5], o[6], o[7]);
            if (WRITE_X && gr < n) {
                *(float4*)&xout[gr * 128 + c0]     = make_float4(o[0], o[1], o[2], o[3]);
                *(float4*)&xout[gr * 128 + c0 + 4] = make_float4(o[4], o[5], o[6], o[7]);
            }
        }
    }
    __syncthreads();

    gemm_core_g(Wjk, a_lds, tx, ty, acc);
    __syncthreads();   // a_lds now free for reduction scratch

    if (LASTB) {
        float bv[8];
        #pragma unroll
        for (int j = 0; j < 8; ++j) bv[j] = bjk[c0 + j];
        #pragma unroll
        for (int i = 0; i < 4; ++i) {
            int gr = row0 + r0 + i;
            if (gr < n) {
                #pragma unroll
                for (int j = 0; j < 8; ++j) acc[i][j] += bv[j];
            }
        }
    }

    int row_last = row0 + 63; if (row_last > n - 1) row_last = n - 1;
    int g_first = batch[row0];
    int g_last  = batch[row_last];
    float* red = &a_lds[0][0];   // 2048 floats scratch
    if (g_first == g_last) {
        float s[8];
        #pragma unroll
        for (int j = 0; j < 8; ++j)
            s[j] = (acc[0][j] + acc[1][j]) + (acc[2][j] + acc[3][j]);
        #pragma unroll
        for (int j = 0; j < 8; ++j) red[ty * 128 + c0 + j] = s[j];
        __syncthreads();
        if (t < 128) {
            float tot = 0.f;
            #pragma unroll
            for (int g = 0; g < 16; ++g) tot += red[g * 128 + t];
            atomicAdd(&pooled[g_first * 128 + t], tot);
        }
    } else {
        #pragma unroll
        for (int i = 0; i < 4; ++i) {
            int gr = row0 + r0 + i;
            if (gr < n) {
                int g = batch[gr];
                #pragma unroll
                for (int j = 0; j < 8; ++j)
                    atomicAdd(&pooled[g * 128 + c0 + j], acc[i][j]);
            }
        }
    }
}

// ---------------- classifier ----------------

__global__ __launch_bounds__(256) void classifier(const float* __restrict__ pooled,
        const float* __restrict__ Wc1, const float* __restrict__ bc1,
        const float* __restrict__ gamma, const float* __restrict__ beta,
        const float* __restrict__ rmean, const float* __restrict__ rvar,
        const float* __restrict__ Wc2, const float* __restrict__ bc2,
        float* __restrict__ out) {
    int g = blockIdx.x, t = threadIdx.x;
    __shared__ float p[128];
    __shared__ float r0[256], r1[256];
    if (t < 128) p[t] = pooled[g * 128 + t];
    __syncthreads();
    float acc = bc1[t];
    #pragma unroll 8
    for (int k = 0; k < 128; ++k) acc += p[k] * Wc1[k * 256 + t];
    float z = (acc - rmean[t]) * rsqrtf(rvar[t] + 1e-5f) * gamma[t] + beta[t];
    z = fmaxf(z, 0.f);
    r0[t] = z * Wc2[t * 2 + 0];
    r1[t] = z * Wc2[t * 2 + 1];
    __syncthreads();
    for (int s = 128; s > 0; s >>= 1) {
        if (t < s) { r0[t] += r0[t + s]; r1[t] += r1[t + s]; }
        __syncthreads();
    }
    if (t == 0) {
        out[g * 2 + 0] = r0[0] + bc2[0];
        out[g * 2 + 1] = r1[0] + bc2[1];
    }
}

// ---------------- launch ----------------

static inline size_t al256(size_t x) { return (x + 255) & ~size_t(255); }

extern "C" void kernel_launch(void* const* d_in, const int* in_sizes, int n_in,
                              void* d_out, int out_size, void* d_ws, size_t ws_size,
                              hipStream_t stream) {
    const float* x    = (const float*)d_in[0];
    const int*   ei   = (const int*)  d_in[1];
    const int*   batch= (const int*)  d_in[3];
    const float* W0a = (const float*)d_in[4];  const float* b0a = (const float*)d_in[5];
    const float* W0b = (const float*)d_in[6];  const float* b0b = (const float*)d_in[7];
    const float* W1a = (const float*)d_in[8];  const float* b1a = (const float*)d_in[9];
    const float* W1b = (const float*)d_in[10]; const float* b1b = (const float*)d_in[11];
    const float* W2a = (const float*)d_in[12]; const float* b2a = (const float*)d_in[13];
    const float* W2b = (const float*)d_in[14]; const float* b2b = (const float*)d_in[15];
    const float* Wjk = (const float*)d_in[16]; const float* bjk = (const float*)d_in[17];
    const float* Wc1 = (const float*)d_in[18]; const float* bc1 = (const float*)d_in[19];
    const float* gamma=(const float*)d_in[20]; const float* beta= (const float*)d_in[21];
    const float* rmean=(const float*)d_in[22]; const float* rvar= (const float*)d_in[23];
    const float* Wc2 = (const float*)d_in[24]; const float* bc2 = (const float*)d_in[25];
    float* out = (float*)d_out;

    const int N = NN, E = EE, B = BB;

    char* w = (char*)d_ws;
    size_t off = 0;
    int* deg    = (int*)(w + off); off = al256(off + (size_t)N * 4);
    int* rowptr = (int*)(w + off); off = al256(off + (size_t)(N + 1) * 4);
    int* cursor = (int*)(w + off); off = al256(off + (size_t)N * 4);
    int* colarr = (int*)(w + off); off = al256(off + (size_t)E * 4);
    int* bsum   = (int*)(w + off); off = al256(off + 1024 * 4);
    float* h0   = (float*)(w + off); off = al256(off + (size_t)N * 8 * 4);
    float* SA   = (float*)(w + off); off = al256(off + (size_t)N * 128 * 4);
    float* SB   = (float*)(w + off); off = al256(off + (size_t)N * 128 * 4);
    float* XC   = (float*)(w + off); off = al256(off + (size_t)N * 128 * 4);
    float* pooled = (float*)(w + off); off = al256(off + (size_t)B * 128 * 4);

    hipMemsetAsync(deg, 0, (size_t)N * 4, stream);
    hipMemsetAsync(pooled, 0, (size_t)B * 128 * 4, stream);

    int nb = (N + 1023) / 1024;   // 98

    count_deg<<<(E + 255) / 256, 256, 0, stream>>>(ei, deg, E);
    scan_partial<<<nb, 256, 0, stream>>>(deg, bsum, N);
    scan_bsum<<<1, 256, 0, stream>>>(bsum, nb);
    scan_apply<<<nb, 256, 0, stream>>>(deg, bsum, rowptr, cursor, N, E);
    fill_csr<<<(E + 255) / 256, 256, 0, stream>>>(ei, cursor, colarr, E);

    int gLin = (N + 63) / 64;   // 1563

    // Layer 0: agg(d=7) -> lin7 (= t0) -> fused [x1; jk0; pool], x1 -> XC
    agg7<<<(N + 31) / 32, 256, 0, stream>>>(x, rowptr, colarr, h0, N);
    lin7<<<(N + 7) / 8, 256, 0, stream>>>(h0, W0a, b0a, SB, N);
    mlp_fused<false, false, false, true><<<gLin, 256, 0, stream>>>(
        SB, rowptr, colarr, nullptr, nullptr, W0b, b0b, Wjk, nullptr,
        batch, XC, pooled, N);

    // Layer 1: gather XC -> MLP -> x2 -> SA (ping-pong; no in-place race)
    mlp_fused<true, true, false, true><<<gLin, 256, 0, stream>>>(
        XC, rowptr, colarr, W1a, b1a, W1b, b1b, Wjk + 128 * 128, nullptr,
        batch, SA, pooled, N);

    // Layer 2: gather SA -> MLP -> jk2 (x3 never materialized)
    mlp_fused<true, true, true, false><<<gLin, 256, 0, stream>>>(
        SA, rowptr, colarr, W2a, b2a, W2b, b2b, Wjk + 256 * 128, bjk,
        batch, nullptr, pooled, N);

    classifier<<<B, 256, 0, stream>>>(pooled, Wc1, bc1, gamma, beta,
                                      rmean, rvar, Wc2, bc2, out);
}

// Round 7
// 1064.544 us; speedup vs baseline: 1.2379x; 1.1153x over previous
//
#include <hip/hip_runtime.h>

#define NN 100000
#define EE 1600000
#define BB 256
#define IN_F 7
#define HH 128

typedef unsigned int uint;
typedef unsigned short ushort;

// ---------------- bf16 helpers ----------------

__device__ __forceinline__ float bflo(uint u) { return __uint_as_float(u << 16); }
__device__ __forceinline__ float bfhi(uint u) { return __uint_as_float(u & 0xFFFF0000u); }
__device__ __forceinline__ ushort f2bf(float x) {   // RNE; inputs are finite
    uint u = __float_as_uint(x);
    u = (u + 0x7FFFu + ((u >> 16) & 1u)) >> 16;
    return (ushort)u;
}

// ---------------- CSR build ----------------

__global__ void count_deg(const int* __restrict__ ei, int* __restrict__ deg, int e) {
    int i = blockIdx.x * 256 + threadIdx.x;
    if (i < e) atomicAdd(&deg[ei[e + i]], 1);   // dst = ei[E + i]
}

__global__ void scan_partial(const int* __restrict__ deg, int* __restrict__ bsum, int n) {
    __shared__ int sd[256];
    int b = blockIdx.x, t = threadIdx.x;
    int base = b * 1024 + t * 4;
    int s = 0;
    #pragma unroll
    for (int k = 0; k < 4; ++k) { int i = base + k; if (i < n) s += deg[i]; }
    sd[t] = s; __syncthreads();
    for (int off = 128; off > 0; off >>= 1) {
        if (t < off) sd[t] += sd[t + off];
        __syncthreads();
    }
    if (t == 0) bsum[b] = sd[0];
}

__global__ void scan_bsum(int* __restrict__ bsum, int nb) {
    __shared__ int sd[256];
    int t = threadIdx.x;
    int v = (t < nb) ? bsum[t] : 0;
    sd[t] = v; __syncthreads();
    for (int off = 1; off < 256; off <<= 1) {
        int add = (t >= off) ? sd[t - off] : 0;
        __syncthreads();
        sd[t] += add;
        __syncthreads();
    }
    if (t < nb) bsum[t] = sd[t] - v;   // exclusive
}

__global__ void scan_apply(const int* __restrict__ deg, const int* __restrict__ bsum,
                           int* __restrict__ rowptr, int* __restrict__ cursor, int n, int e) {
    __shared__ int sd[256];
    int b = blockIdx.x, t = threadIdx.x;
    int base = b * 1024 + t * 4;
    int v[4]; int s = 0;
    #pragma unroll
    for (int k = 0; k < 4; ++k) { int i = base + k; v[k] = (i < n) ? deg[i] : 0; s += v[k]; }
    sd[t] = s; __syncthreads();
    int mine = s;
    for (int off = 1; off < 256; off <<= 1) {
        int add = (t >= off) ? sd[t - off] : 0;
        __syncthreads();
        sd[t] += add;
        __syncthreads();
    }
    int run = sd[t] - mine + bsum[b];
    #pragma unroll
    for (int k = 0; k < 4; ++k) {
        int i = base + k;
        if (i < n) { rowptr[i] = run; cursor[i] = run; }
        run += v[k];
    }
    if (b == 0 && t == 0) rowptr[n] = e;
}

__global__ void fill_csr(const int* __restrict__ ei, int* __restrict__ cursor,
                         int* __restrict__ colarr, int e) {
    int i = blockIdx.x * 256 + threadIdx.x;
    if (i < e) {
        int d = ei[e + i];
        int pos = atomicAdd(&cursor[d], 1);
        colarr[pos] = ei[i];   // src
    }
}

// ---------------- layer-0 aggregation (d=7) ----------------

__global__ __launch_bounds__(256) void agg7(const float* __restrict__ xin,
        const int* __restrict__ rowptr, const int* __restrict__ colarr,
        float* __restrict__ h0, int n) {
    int node = blockIdx.x * 32 + (threadIdx.x >> 3);
    int f = threadIdx.x & 7;
    if (node >= n) return;
    int fidx = (f < 7) ? f : 0;
    float acc = xin[node * 7 + fidx];
    int beg = rowptr[node], end = rowptr[node + 1];
    int j = beg;
    for (; j + 4 <= end; j += 4) {
        int s0 = colarr[j], s1 = colarr[j+1], s2 = colarr[j+2], s3 = colarr[j+3];
        float v0 = xin[s0*7 + fidx], v1 = xin[s1*7 + fidx];
        float v2 = xin[s2*7 + fidx], v3 = xin[s3*7 + fidx];
        acc += (v0 + v1) + (v2 + v3);
    }
    for (; j < end; ++j) acc += xin[colarr[j]*7 + fidx];
    h0[node * 8 + f] = (f < 7) ? acc : 0.f;
}

// ---------------- small first linear ----------------

__global__ __launch_bounds__(256) void lin7(const float* __restrict__ h0,
        const float* __restrict__ W, const float* __restrict__ bias,
        float* __restrict__ out, int n) {
    __shared__ float wl[7][128];
    __shared__ float hl[8][8];
    int t = threadIdx.x;
    for (int l = t; l < 7 * 128; l += 256) wl[l >> 7][l & 127] = W[l];
    int row0 = blockIdx.x * 8;
    if (t < 64) {
        int r = t >> 3, k = t & 7;
        int gr = row0 + r;
        hl[r][k] = (gr < n) ? h0[gr * 8 + k] : 0.f;
    }
    __syncthreads();
    int c = t & 127, g = t >> 7;
    float bv = bias[c];
    #pragma unroll
    for (int i = 0; i < 4; ++i) {
        int r = g * 4 + i, gr = row0 + r;
        if (gr < n) {
            float acc = bv;
            #pragma unroll
            for (int k = 0; k < 7; ++k) acc += hl[r][k] * wl[k][c];
            out[gr * 128 + c] = fmaxf(acc, 0.f);
        }
    }
}

// ------- fused [bf16 aggregate] + MLP + JK + pool (256 threads, 4x8 microtile) -------

// XOR swizzle: logical col c of row r lives at physical col c ^ swz(r).
__device__ __forceinline__ int swz(int r) { return ((r >> 2) & 7) * 4; }

// acc[4][8] = a_lds(64x128, swizzled) @ W(128x128, global/L1-L2).
__device__ __forceinline__ void gemm_core_g(const float* __restrict__ W,
        const float (&a_lds)[64][128], int tx, int ty, float (&acc)[4][8])
{
    #pragma unroll
    for (int i = 0; i < 4; ++i)
        #pragma unroll
        for (int j = 0; j < 8; ++j) acc[i][j] = 0.f;
    const float* Wp = W + tx * 8;
    const int r0 = ty * 4;
    for (int kk = 0; kk < 128; kk += 4) {
        float4 af[4];
        #pragma unroll
        for (int i = 0; i < 4; ++i)
            af[i] = *(const float4*)&a_lds[r0 + i][kk ^ swz(r0 + i)];
        #pragma unroll
        for (int dk = 0; dk < 4; ++dk) {
            float4 w0 = *(const float4*)&Wp[(kk + dk) * 128];
            float4 w1 = *(const float4*)&Wp[(kk + dk) * 128 + 4];
            #pragma unroll
            for (int i = 0; i < 4; ++i) {
                float av = (dk == 0) ? af[i].x : (dk == 1) ? af[i].y
                         : (dk == 2) ? af[i].z : af[i].w;
                acc[i][0] += av * w0.x; acc[i][1] += av * w0.y;
                acc[i][2] += av * w0.z; acc[i][3] += av * w0.w;
                acc[i][4] += av * w1.x; acc[i][5] += av * w1.y;
                acc[i][6] += av * w1.z; acc[i][7] += av * w1.w;
            }
        }
    }
}

// Per layer: [agg via CSR, bf16 in] ; [t = relu(agg@Wa+ba)] ; x = relu(t@Wb+bb) ;
//            y = x@Wjk(+bjk) ; pooled[batch] += y ; [xout_bf = bf16(x)]
// GATHER: in_bf (bf16) self + neighbors, fp32 accumulate.  !GATHER: in_f32 staging.
template<bool GATHER, bool DO_A, bool LASTB, bool WRITE_X>
__global__ __launch_bounds__(256) void mlp_fused(
        const float* __restrict__ in_f32, const ushort* __restrict__ in_bf,
        const int* __restrict__ rowptr, const int* __restrict__ colarr,
        const float* __restrict__ Wa, const float* __restrict__ ba,
        const float* __restrict__ Wb, const float* __restrict__ bb,
        const float* __restrict__ Wjk, const float* __restrict__ bjk,
        const int* __restrict__ batch,
        ushort* __restrict__ xout_bf, float* __restrict__ pooled, int n)
{
    __shared__ float a_lds[64][128];   // 32 KB
    int t = threadIdx.x, tx = t & 15, ty = t >> 4;   // tx 0..15, ty 0..15
    int row0 = blockIdx.x * 64;
    int c0 = tx * 8, r0 = ty * 4;
    float acc[4][8];

    if (GATHER) {
        // 4 threads/row; thread q covers 8-elem chunks {q,4+q,8+q,12+q} (uint4 = 8 bf16)
        int r = t >> 2, q = t & 3;
        int gr = row0 + r;
        float f[4][8];
        #pragma unroll
        for (int i = 0; i < 4; ++i)
            #pragma unroll
            for (int j = 0; j < 8; ++j) f[i][j] = 0.f;
        if (gr < n) {
            const uint4* sp = (const uint4*)(in_bf + (size_t)gr * 128);
            #pragma unroll
            for (int i = 0; i < 4; ++i) {
                uint4 v = sp[i * 4 + q];
                f[i][0] = bflo(v.x); f[i][1] = bfhi(v.x);
                f[i][2] = bflo(v.y); f[i][3] = bfhi(v.y);
                f[i][4] = bflo(v.z); f[i][5] = bfhi(v.z);
                f[i][6] = bflo(v.w); f[i][7] = bfhi(v.w);
            }
            int beg = rowptr[gr], end = rowptr[gr + 1];
            for (int j = beg; j < end; ++j) {
                const uint4* np = (const uint4*)(in_bf + (size_t)colarr[j] * 128);
                #pragma unroll
                for (int i = 0; i < 4; ++i) {
                    uint4 v = np[i * 4 + q];
                    f[i][0] += bflo(v.x); f[i][1] += bfhi(v.x);
                    f[i][2] += bflo(v.y); f[i][3] += bfhi(v.y);
                    f[i][4] += bflo(v.z); f[i][5] += bfhi(v.z);
                    f[i][6] += bflo(v.w); f[i][7] += bfhi(v.w);
                }
            }
        }
        int s = swz(r);
        #pragma unroll
        for (int i = 0; i < 4; ++i) {
            int c = (i * 4 + q) * 8;
            *(float4*)&a_lds[r][c ^ s]       = make_float4(f[i][0], f[i][1], f[i][2], f[i][3]);
            *(float4*)&a_lds[r][(c + 4) ^ s] = make_float4(f[i][4], f[i][5], f[i][6], f[i][7]);
        }
    } else {
        #pragma unroll
        for (int it = 0; it < 8; ++it) {
            int l = t + 256 * it;
            int r = l >> 5, c4 = (l & 31) * 4;
            int gr = row0 + r;
            float4 av = make_float4(0.f, 0.f, 0.f, 0.f);
            if (gr < n) av = *(const float4*)&in_f32[gr * 128 + c4];
            *(float4*)&a_lds[r][c4 ^ swz(r)] = av;
        }
    }
    __syncthreads();

    if (DO_A) {
        gemm_core_g(Wa, a_lds, tx, ty, acc);
        __syncthreads();
        float bv[8];
        #pragma unroll
        for (int j = 0; j < 8; ++j) bv[j] = ba[c0 + j];
        #pragma unroll
        for (int i = 0; i < 4; ++i) {
            int r = r0 + i, gr = row0 + r;
            float o[8];
            #pragma unroll
            for (int j = 0; j < 8; ++j)
                o[j] = (gr < n) ? fmaxf(acc[i][j] + bv[j], 0.f) : 0.f;
            int s = swz(r);
            *(float4*)&a_lds[r][c0 ^ s]       = make_float4(o[0], o[1], o[2], o[3]);
            *(float4*)&a_lds[r][(c0 + 4) ^ s] = make_float4(o[4], o[5], o[6], o[7]);
        }
        __syncthreads();
    }

    gemm_core_g(Wb, a_lds, tx, ty, acc);
    __syncthreads();
    {
        float bv[8];
        #pragma unroll
        for (int j = 0; j < 8; ++j) bv[j] = bb[c0 + j];
        #pragma unroll
        for (int i = 0; i < 4; ++i) {
            int r = r0 + i, gr = row0 + r;
            float o[8];
            #pragma unroll
            for (int j = 0; j < 8; ++j)
                o[j] = (gr < n) ? fmaxf(acc[i][j] + bv[j], 0.f) : 0.f;
            int s = swz(r);
            *(float4*)&a_lds[r][c0 ^ s]       = make_float4(o[0], o[1], o[2], o[3]);
            *(float4*)&a_lds[r][(c0 + 4) ^ s] = make_float4(o[4], o[5], o[6], o[7]);
            if (WRITE_X && gr < n) {
                uint4 pk;
                pk.x = (uint)f2bf(o[0]) | ((uint)f2bf(o[1]) << 16);
                pk.y = (uint)f2bf(o[2]) | ((uint)f2bf(o[3]) << 16);
                pk.z = (uint)f2bf(o[4]) | ((uint)f2bf(o[5]) << 16);
                pk.w = (uint)f2bf(o[6]) | ((uint)f2bf(o[7]) << 16);
                *(uint4*)(xout_bf + (size_t)gr * 128 + c0) = pk;
            }
        }
    }
    __syncthreads();

    gemm_core_g(Wjk, a_lds, tx, ty, acc);
    __syncthreads();   // a_lds now free for reduction scratch

    if (LASTB) {
        float bv[8];
        #pragma unroll
        for (int j = 0; j < 8; ++j) bv[j] = bjk[c0 + j];
        #pragma unroll
        for (int i = 0; i < 4; ++i) {
            int gr = row0 + r0 + i;
            if (gr < n) {
                #pragma unroll
                for (int j = 0; j < 8; ++j) acc[i][j] += bv[j];
            }
        }
    }

    int row_last = row0 + 63; if (row_last > n - 1) row_last = n - 1;
    int g_first = batch[row0];
    int g_last  = batch[row_last];
    float* red = &a_lds[0][0];   // 2048 floats scratch
    if (g_first == g_last) {
        float s[8];
        #pragma unroll
        for (int j = 0; j < 8; ++j)
            s[j] = (acc[0][j] + acc[1][j]) + (acc[2][j] + acc[3][j]);
        #pragma unroll
        for (int j = 0; j < 8; ++j) red[ty * 128 + c0 + j] = s[j];
        __syncthreads();
        if (t < 128) {
            float tot = 0.f;
            #pragma unroll
            for (int g = 0; g < 16; ++g) tot += red[g * 128 + t];
            atomicAdd(&pooled[g_first * 128 + t], tot);
        }
    } else {
        #pragma unroll
        for (int i = 0; i < 4; ++i) {
            int gr = row0 + r0 + i;
            if (gr < n) {
                int g = batch[gr];
                #pragma unroll
                for (int j = 0; j < 8; ++j)
                    atomicAdd(&pooled[g * 128 + c0 + j], acc[i][j]);
            }
        }
    }
}

// ---------------- classifier ----------------

__global__ __launch_bounds__(256) void classifier(const float* __restrict__ pooled,
        const float* __restrict__ Wc1, const float* __restrict__ bc1,
        const float* __restrict__ gamma, const float* __restrict__ beta,
        const float* __restrict__ rmean, const float* __restrict__ rvar,
        const float* __restrict__ Wc2, const float* __restrict__ bc2,
        float* __restrict__ out) {
    int g = blockIdx.x, t = threadIdx.x;
    __shared__ float p[128];
    __shared__ float r0[256], r1[256];
    if (t < 128) p[t] = pooled[g * 128 + t];
    __syncthreads();
    float acc = bc1[t];
    #pragma unroll 8
    for (int k = 0; k < 128; ++k) acc += p[k] * Wc1[k * 256 + t];
    float z = (acc - rmean[t]) * rsqrtf(rvar[t] + 1e-5f) * gamma[t] + beta[t];
    z = fmaxf(z, 0.f);
    r0[t] = z * Wc2[t * 2 + 0];
    r1[t] = z * Wc2[t * 2 + 1];
    __syncthreads();
    for (int s = 128; s > 0; s >>= 1) {
        if (t < s) { r0[t] += r0[t + s]; r1[t] += r1[t + s]; }
        __syncthreads();
    }
    if (t == 0) {
        out[g * 2 + 0] = r0[0] + bc2[0];
        out[g * 2 + 1] = r1[0] + bc2[1];
    }
}

// ---------------- launch ----------------

static inline size_t al256(size_t x) { return (x + 255) & ~size_t(255); }

extern "C" void kernel_launch(void* const* d_in, const int* in_sizes, int n_in,
                              void* d_out, int out_size, void* d_ws, size_t ws_size,
                              hipStream_t stream) {
    const float* x    = (const float*)d_in[0];
    const int*   ei   = (const int*)  d_in[1];
    const int*   batch= (const int*)  d_in[3];
    const float* W0a = (const float*)d_in[4];  const float* b0a = (const float*)d_in[5];
    const float* W0b = (const float*)d_in[6];  const float* b0b = (const float*)d_in[7];
    const float* W1a = (const float*)d_in[8];  const float* b1a = (const float*)d_in[9];
    const float* W1b = (const float*)d_in[10]; const float* b1b = (const float*)d_in[11];
    const float* W2a = (const float*)d_in[12]; const float* b2a = (const float*)d_in[13];
    const float* W2b = (const float*)d_in[14]; const float* b2b = (const float*)d_in[15];
    const float* Wjk = (const float*)d_in[16]; const float* bjk = (const float*)d_in[17];
    const float* Wc1 = (const float*)d_in[18]; const float* bc1 = (const float*)d_in[19];
    const float* gamma=(const float*)d_in[20]; const float* beta= (const float*)d_in[21];
    const float* rmean=(const float*)d_in[22]; const float* rvar= (const float*)d_in[23];
    const float* Wc2 = (const float*)d_in[24]; const float* bc2 = (const float*)d_in[25];
    float* out = (float*)d_out;

    const int N = NN, E = EE, B = BB;

    char* w = (char*)d_ws;
    size_t off = 0;
    int* deg    = (int*)(w + off); off = al256(off + (size_t)N * 4);
    int* rowptr = (int*)(w + off); off = al256(off + (size_t)(N + 1) * 4);
    int* cursor = (int*)(w + off); off = al256(off + (size_t)N * 4);
    int* colarr = (int*)(w + off); off = al256(off + (size_t)E * 4);
    int* bsum   = (int*)(w + off); off = al256(off + 1024 * 4);
    float* h0   = (float*)(w + off); off = al256(off + (size_t)N * 8 * 4);
    float* SB   = (float*)(w + off); off = al256(off + (size_t)N * 128 * 4);
    ushort* XB1 = (ushort*)(w + off); off = al256(off + (size_t)N * 128 * 2);
    ushort* XB2 = (ushort*)(w + off); off = al256(off + (size_t)N * 128 * 2);
    float* pooled = (float*)(w + off); off = al256(off + (size_t)B * 128 * 4);

    hipMemsetAsync(deg, 0, (size_t)N * 4, stream);
    hipMemsetAsync(pooled, 0, (size_t)B * 128 * 4, stream);

    int nb = (N + 1023) / 1024;   // 98

    count_deg<<<(E + 255) / 256, 256, 0, stream>>>(ei, deg, E);
    scan_partial<<<nb, 256, 0, stream>>>(deg, bsum, N);
    scan_bsum<<<1, 256, 0, stream>>>(bsum, nb);
    scan_apply<<<nb, 256, 0, stream>>>(deg, bsum, rowptr, cursor, N, E);
    fill_csr<<<(E + 255) / 256, 256, 0, stream>>>(ei, cursor, colarr, E);

    int gLin = (N + 63) / 64;   // 1563

    // Layer 0: agg(d=7) -> lin7 (= t0) -> fused [x1; jk0; pool], x1 -> XB1 (bf16)
    agg7<<<(N + 31) / 32, 256, 0, stream>>>(x, rowptr, colarr, h0, N);
    lin7<<<(N + 7) / 8, 256, 0, stream>>>(h0, W0a, b0a, SB, N);
    mlp_fused<false, false, false, true><<<gLin, 256, 0, stream>>>(
        SB, nullptr, rowptr, colarr, nullptr, nullptr, W0b, b0b, Wjk, nullptr,
        batch, XB1, pooled, N);

    // Layer 1: bf16 gather XB1 -> MLP -> x2 -> XB2 (bf16)
    mlp_fused<true, true, false, true><<<gLin, 256, 0, stream>>>(
        nullptr, XB1, rowptr, colarr, W1a, b1a, W1b, b1b, Wjk + 128 * 128, nullptr,
        batch, XB2, pooled, N);

    // Layer 2: bf16 gather XB2 -> MLP -> jk2 (x3 never materialized)
    mlp_fused<true, true, true, false><<<gLin, 256, 0, stream>>>(
        nullptr, XB2, rowptr, colarr, W2a, b2a, W2b, b2b, Wjk + 256 * 128, bjk,
        batch, nullptr, pooled, N);

    classifier<<<B, 256, 0, stream>>>(pooled, Wc1, bc1, gamma, beta,
                                      rmean, rvar, Wc2, bc2, out);
}

// Round 8
// 729.929 us; speedup vs baseline: 1.8054x; 1.4584x over previous
//
#include <hip/hip_runtime.h>

#define NN 100000
#define EE 1600000
#define BB 256
#define IN_F 7
#define HH 128

typedef unsigned int uint;
typedef unsigned short ushort;
typedef __attribute__((ext_vector_type(8))) short short8;
typedef __attribute__((ext_vector_type(4))) float f32x4;

// ---------------- bf16 helpers ----------------

__device__ __forceinline__ float bflo(uint u) { return __uint_as_float(u << 16); }
__device__ __forceinline__ float bfhi(uint u) { return __uint_as_float(u & 0xFFFF0000u); }
__device__ __forceinline__ ushort f2bf(float x) {   // RNE; inputs finite
    uint u = __float_as_uint(x);
    u = (u + 0x7FFFu + ((u >> 16) & 1u)) >> 16;
    return (ushort)u;
}

// ---------------- CSR build ----------------

__global__ void count_deg(const int* __restrict__ ei, int* __restrict__ deg, int e) {
    int i = blockIdx.x * 256 + threadIdx.x;
    if (i < e) atomicAdd(&deg[ei[e + i]], 1);   // dst = ei[E + i]
}

__global__ void scan_partial(const int* __restrict__ deg, int* __restrict__ bsum, int n) {
    __shared__ int sd[256];
    int b = blockIdx.x, t = threadIdx.x;
    int base = b * 1024 + t * 4;
    int s = 0;
    #pragma unroll
    for (int k = 0; k < 4; ++k) { int i = base + k; if (i < n) s += deg[i]; }
    sd[t] = s; __syncthreads();
    for (int off = 128; off > 0; off >>= 1) {
        if (t < off) sd[t] += sd[t + off];
        __syncthreads();
    }
    if (t == 0) bsum[b] = sd[0];
}

__global__ void scan_bsum(int* __restrict__ bsum, int nb) {
    __shared__ int sd[256];
    int t = threadIdx.x;
    int v = (t < nb) ? bsum[t] : 0;
    sd[t] = v; __syncthreads();
    for (int off = 1; off < 256; off <<= 1) {
        int add = (t >= off) ? sd[t - off] : 0;
        __syncthreads();
        sd[t] += add;
        __syncthreads();
    }
    if (t < nb) bsum[t] = sd[t] - v;   // exclusive
}

__global__ void scan_apply(const int* __restrict__ deg, const int* __restrict__ bsum,
                           int* __restrict__ rowptr, int* __restrict__ cursor, int n, int e) {
    __shared__ int sd[256];
    int b = blockIdx.x, t = threadIdx.x;
    int base = b * 1024 + t * 4;
    int v[4]; int s = 0;
    #pragma unroll
    for (int k = 0; k < 4; ++k) { int i = base + k; v[k] = (i < n) ? deg[i] : 0; s += v[k]; }
    sd[t] = s; __syncthreads();
    int mine = s;
    for (int off = 1; off < 256; off <<= 1) {
        int add = (t >= off) ? sd[t - off] : 0;
        __syncthreads();
        sd[t] += add;
        __syncthreads();
    }
    int run = sd[t] - mine + bsum[b];
    #pragma unroll
    for (int k = 0; k < 4; ++k) {
        int i = base + k;
        if (i < n) { rowptr[i] = run; cursor[i] = run; }
        run += v[k];
    }
    if (b == 0 && t == 0) rowptr[n] = e;
}

__global__ void fill_csr(const int* __restrict__ ei, int* __restrict__ cursor,
                         int* __restrict__ colarr, int e) {
    int i = blockIdx.x * 256 + threadIdx.x;
    if (i < e) {
        int d = ei[e + i];
        int pos = atomicAdd(&cursor[d], 1);
        colarr[pos] = ei[i];   // src
    }
}

// ---------------- weight pre-split into MFMA B-fragment layout ----------------
// For mfma_f32_16x16x32_bf16, B operand: lane holds B[k = (lane>>4)*8 + j][n = lane&15],
// j=0..7. Frag storage: [(kc*8+nt)*64 + lane] * 8 + j  (kc: k/32, nt: n/16).
// hi = bf16(W), lo = bf16(W - hi): 3-product emulation gives ~2^-16 rel error.

__global__ void wsplit(const float* __restrict__ W, ushort* __restrict__ hi,
                       ushort* __restrict__ lo) {
    int idx = blockIdx.x * 256 + threadIdx.x;   // 0..16383
    int j = idx & 7, l = (idx >> 3) & 63, blk = idx >> 9;
    int kc = blk >> 3, nt = blk & 7;
    int k = kc * 32 + (l >> 4) * 8 + j;
    int n = nt * 16 + (l & 15);
    float f = W[k * 128 + n];
    ushort h = f2bf(f);
    float hf = __uint_as_float((uint)h << 16);
    hi[idx] = h;
    lo[idx] = f2bf(f - hf);
}

// ---------------- layer-0 aggregation (d=7) ----------------

__global__ __launch_bounds__(256) void agg7(const float* __restrict__ xin,
        const int* __restrict__ rowptr, const int* __restrict__ colarr,
        float* __restrict__ h0, int n) {
    int node = blockIdx.x * 32 + (threadIdx.x >> 3);
    int f = threadIdx.x & 7;
    if (node >= n) return;
    int fidx = (f < 7) ? f : 0;
    float acc = xin[node * 7 + fidx];
    int beg = rowptr[node], end = rowptr[node + 1];
    int j = beg;
    for (; j + 4 <= end; j += 4) {
        int s0 = colarr[j], s1 = colarr[j+1], s2 = colarr[j+2], s3 = colarr[j+3];
        float v0 = xin[s0*7 + fidx], v1 = xin[s1*7 + fidx];
        float v2 = xin[s2*7 + fidx], v3 = xin[s3*7 + fidx];
        acc += (v0 + v1) + (v2 + v3);
    }
    for (; j < end; ++j) acc += xin[colarr[j]*7 + fidx];
    h0[node * 8 + f] = (f < 7) ? acc : 0.f;
}

// ---------------- small first linear ----------------

__global__ __launch_bounds__(256) void lin7(const float* __restrict__ h0,
        const float* __restrict__ W, const float* __restrict__ bias,
        float* __restrict__ out, int n) {
    __shared__ float wl[7][128];
    __shared__ float hl[8][8];
    int t = threadIdx.x;
    for (int l = t; l < 7 * 128; l += 256) wl[l >> 7][l & 127] = W[l];
    int row0 = blockIdx.x * 8;
    if (t < 64) {
        int r = t >> 3, k = t & 7;
        int gr = row0 + r;
        hl[r][k] = (gr < n) ? h0[gr * 8 + k] : 0.f;
    }
    __syncthreads();
    int c = t & 127, g = t >> 7;
    float bv = bias[c];
    #pragma unroll
    for (int i = 0; i < 4; ++i) {
        int r = g * 4 + i, gr = row0 + r;
        if (gr < n) {
            float acc = bv;
            #pragma unroll
            for (int k = 0; k < 7; ++k) acc += hl[r][k] * wl[k][c];
            out[gr * 128 + c] = fmaxf(acc, 0.f);
        }
    }
}

// ------- fused [bf16 aggregate] + MFMA MLP + JK + pool (256 thr = 4 waves) -------

// XOR swizzle: logical col c of row r lives at physical col c ^ swz(r) (4-col granule).
__device__ __forceinline__ int swz(int r) { return ((r >> 2) & 7) * 4; }

// acc[nt] = D tile (16 rows mt..mt+15) x (16 cols nt*16..+15); bf16x3 split emulation.
__device__ __forceinline__ void gemm_mfma(
        const ushort* __restrict__ WH, const ushort* __restrict__ WL,
        const float (&a_lds)[64][128], int mt, int lm, int lq, int l,
        f32x4 (&acc)[8])
{
    #pragma unroll
    for (int nt = 0; nt < 8; ++nt) acc[nt] = (f32x4){0.f, 0.f, 0.f, 0.f};
    const short8* BH = (const short8*)WH;
    const short8* BL = (const short8*)WL;
    int m = mt + lm;
    int s = swz(m);
    #pragma unroll
    for (int kc = 0; kc < 4; ++kc) {
        int cb = kc * 32 + lq * 8;
        float4 a0 = *(const float4*)&a_lds[m][cb ^ s];
        float4 a1 = *(const float4*)&a_lds[m][(cb + 4) ^ s];
        float av[8] = {a0.x, a0.y, a0.z, a0.w, a1.x, a1.y, a1.z, a1.w};
        short8 ah, al8;
        #pragma unroll
        for (int j = 0; j < 8; ++j) {
            ushort h = f2bf(av[j]);
            ah[j] = (short)h;
            float hf = __uint_as_float((uint)h << 16);
            al8[j] = (short)f2bf(av[j] - hf);
        }
        #pragma unroll
        for (int nt = 0; nt < 8; ++nt) {
            short8 bh = BH[(kc * 8 + nt) * 64 + l];
            short8 bl = BL[(kc * 8 + nt) * 64 + l];
            acc[nt] = __builtin_amdgcn_mfma_f32_16x16x32_bf16(ah,  bh, acc[nt], 0, 0, 0);
            acc[nt] = __builtin_amdgcn_mfma_f32_16x16x32_bf16(al8, bh, acc[nt], 0, 0, 0);
            acc[nt] = __builtin_amdgcn_mfma_f32_16x16x32_bf16(ah,  bl, acc[nt], 0, 0, 0);
        }
    }
}

// D layout: value (nt, r) sits at row = mt + lq*4 + r, col = nt*16 + lm.
__device__ __forceinline__ void epi_store(f32x4 (&acc)[8], const float* __restrict__ bias,
        float (&a_lds)[64][128], int row0, int n, int mt, int lm, int lq,
        ushort* __restrict__ xout)
{
    #pragma unroll
    for (int nt = 0; nt < 8; ++nt) {
        int col = nt * 16 + lm;
        float bv = bias[col];
        #pragma unroll
        for (int r = 0; r < 4; ++r) {
            int row = mt + lq * 4 + r;
            int gr = row0 + row;
            float v = fmaxf(acc[nt][r] + bv, 0.f);
            if (gr >= n) v = 0.f;
            a_lds[row][col ^ swz(row)] = v;
            if (xout != nullptr && gr < n)
                xout[(size_t)gr * 128 + col] = f2bf(v);
        }
    }
}

template<bool GATHER, bool DO_A, bool LASTB, bool WRITE_X>
__global__ __launch_bounds__(256) void mlp_fused(
        const float* __restrict__ in_f32, const ushort* __restrict__ in_bf,
        const int* __restrict__ rowptr, const int* __restrict__ colarr,
        const ushort* __restrict__ WaH, const ushort* __restrict__ WaL,
        const float* __restrict__ ba,
        const ushort* __restrict__ WbH, const ushort* __restrict__ WbL,
        const float* __restrict__ bb,
        const ushort* __restrict__ WjH, const ushort* __restrict__ WjL,
        const float* __restrict__ bjk,
        const int* __restrict__ batch,
        ushort* __restrict__ xout_bf, float* __restrict__ pooled, int n)
{
    __shared__ float a_lds[64][128];   // 32 KB
    int t = threadIdx.x;
    int row0 = blockIdx.x * 64;

    if (GATHER) {
        // 4 threads/row; thread q covers 8-elem chunks {q,4+q,8+q,12+q} (uint4 = 8 bf16)
        int r = t >> 2, q = t & 3;
        int gr = row0 + r;
        float f[4][8];
        #pragma unroll
        for (int i = 0; i < 4; ++i)
            #pragma unroll
            for (int j = 0; j < 8; ++j) f[i][j] = 0.f;
        if (gr < n) {
            const uint4* sp = (const uint4*)(in_bf + (size_t)gr * 128);
            #pragma unroll
            for (int i = 0; i < 4; ++i) {
                uint4 v = sp[i * 4 + q];
                f[i][0] = bflo(v.x); f[i][1] = bfhi(v.x);
                f[i][2] = bflo(v.y); f[i][3] = bfhi(v.y);
                f[i][4] = bflo(v.z); f[i][5] = bfhi(v.z);
                f[i][6] = bflo(v.w); f[i][7] = bfhi(v.w);
            }
            int beg = rowptr[gr], end = rowptr[gr + 1];
            for (int j = beg; j < end; ++j) {
                const uint4* np = (const uint4*)(in_bf + (size_t)colarr[j] * 128);
                #pragma unroll
                for (int i = 0; i < 4; ++i) {
                    uint4 v = np[i * 4 + q];
                    f[i][0] += bflo(v.x); f[i][1] += bfhi(v.x);
                    f[i][2] += bflo(v.y); f[i][3] += bfhi(v.y);
                    f[i][4] += bflo(v.z); f[i][5] += bfhi(v.z);
                    f[i][6] += bflo(v.w); f[i][7] += bfhi(v.w);
                }
            }
        }
        int s = swz(r);
        #pragma unroll
        for (int i = 0; i < 4; ++i) {
            int c = (i * 4 + q) * 8;
            *(float4*)&a_lds[r][c ^ s]       = make_float4(f[i][0], f[i][1], f[i][2], f[i][3]);
            *(float4*)&a_lds[r][(c + 4) ^ s] = make_float4(f[i][4], f[i][5], f[i][6], f[i][7]);
        }
    } else {
        #pragma unroll
        for (int it = 0; it < 8; ++it) {
            int l = t + 256 * it;
            int r = l >> 5, c4 = (l & 31) * 4;
            int gr = row0 + r;
            float4 av = make_float4(0.f, 0.f, 0.f, 0.f);
            if (gr < n) av = *(const float4*)&in_f32[gr * 128 + c4];
            *(float4*)&a_lds[r][c4 ^ swz(r)] = av;
        }
    }
    __syncthreads();

    int w = t >> 6, l = t & 63;
    int mt = w * 16, lm = l & 15, lq = l >> 4;
    f32x4 acc[8];

    if (DO_A) {
        gemm_mfma(WaH, WaL, a_lds, mt, lm, lq, l, acc);
        __syncthreads();
        epi_store(acc, ba, a_lds, row0, n, mt, lm, lq, nullptr);
        __syncthreads();
    }

    gemm_mfma(WbH, WbL, a_lds, mt, lm, lq, l, acc);
    __syncthreads();
    epi_store(acc, bb, a_lds, row0, n, mt, lm, lq, WRITE_X ? xout_bf : nullptr);
    __syncthreads();

    gemm_mfma(WjH, WjL, a_lds, mt, lm, lq, l, acc);
    __syncthreads();

    // JK epilogue: +bjk (last layer), mask invalid rows, stage y into a_lds
    #pragma unroll
    for (int nt = 0; nt < 8; ++nt) {
        int col = nt * 16 + lm;
        float bv = LASTB ? bjk[col] : 0.f;
        #pragma unroll
        for (int r = 0; r < 4; ++r) {
            int row = mt + lq * 4 + r;
            int gr = row0 + row;
            float v = acc[nt][r] + bv;
            if (gr >= n) v = 0.f;
            a_lds[row][col ^ swz(row)] = v;
        }
    }
    __syncthreads();

    // pooling
    int row_last = row0 + 63; if (row_last > n - 1) row_last = n - 1;
    int g_first = batch[row0];
    int g_last  = batch[row_last];
    int c = t & 127, half = t >> 7;
    if (g_first == g_last) {
        float sacc = 0.f;
        for (int r = half * 32; r < half * 32 + 32; ++r)
            sacc += a_lds[r][c ^ swz(r)];
        __syncthreads();
        a_lds[half][c] = sacc;
        __syncthreads();
        if (t < 128)
            atomicAdd(&pooled[g_first * 128 + t], a_lds[0][t] + a_lds[1][t]);
    } else {
        float sacc = 0.f; int gprev = -1;
        for (int r = half * 32; r < half * 32 + 32; ++r) {
            int gr = row0 + r;
            if (gr >= n) break;
            int g = batch[gr];
            if (g != gprev) {
                if (gprev >= 0) atomicAdd(&pooled[gprev * 128 + c], sacc);
                sacc = 0.f; gprev = g;
            }
            sacc += a_lds[r][c ^ swz(r)];
        }
        if (gprev >= 0) atomicAdd(&pooled[gprev * 128 + c], sacc);
    }
}

// ---------------- classifier ----------------

__global__ __launch_bounds__(256) void classifier(const float* __restrict__ pooled,
        const float* __restrict__ Wc1, const float* __restrict__ bc1,
        const float* __restrict__ gamma, const float* __restrict__ beta,
        const float* __restrict__ rmean, const float* __restrict__ rvar,
        const float* __restrict__ Wc2, const float* __restrict__ bc2,
        float* __restrict__ out) {
    int g = blockIdx.x, t = threadIdx.x;
    __shared__ float p[128];
    __shared__ float r0[256], r1[256];
    if (t < 128) p[t] = pooled[g * 128 + t];
    __syncthreads();
    float acc = bc1[t];
    #pragma unroll 8
    for (int k = 0; k < 128; ++k) acc += p[k] * Wc1[k * 256 + t];
    float z = (acc - rmean[t]) * rsqrtf(rvar[t] + 1e-5f) * gamma[t] + beta[t];
    z = fmaxf(z, 0.f);
    r0[t] = z * Wc2[t * 2 + 0];
    r1[t] = z * Wc2[t * 2 + 1];
    __syncthreads();
    for (int s = 128; s > 0; s >>= 1) {
        if (t < s) { r0[t] += r0[t + s]; r1[t] += r1[t + s]; }
        __syncthreads();
    }
    if (t == 0) {
        out[g * 2 + 0] = r0[0] + bc2[0];
        out[g * 2 + 1] = r1[0] + bc2[1];
    }
}

// ---------------- launch ----------------

static inline size_t al256(size_t x) { return (x + 255) & ~size_t(255); }

extern "C" void kernel_launch(void* const* d_in, const int* in_sizes, int n_in,
                              void* d_out, int out_size, void* d_ws, size_t ws_size,
                              hipStream_t stream) {
    const float* x    = (const float*)d_in[0];
    const int*   ei   = (const int*)  d_in[1];
    const int*   batch= (const int*)  d_in[3];
    const float* W0a = (const float*)d_in[4];  const float* b0a = (const float*)d_in[5];
    const float* W0b = (const float*)d_in[6];  const float* b0b = (const float*)d_in[7];
    const float* W1a = (const float*)d_in[8];  const float* b1a = (const float*)d_in[9];
    const float* W1b = (const float*)d_in[10]; const float* b1b = (const float*)d_in[11];
    const float* W2a = (const float*)d_in[12]; const float* b2a = (const float*)d_in[13];
    const float* W2b = (const float*)d_in[14]; const float* b2b = (const float*)d_in[15];
    const float* Wjk = (const float*)d_in[16]; const float* bjk = (const float*)d_in[17];
    const float* Wc1 = (const float*)d_in[18]; const float* bc1 = (const float*)d_in[19];
    const float* gamma=(const float*)d_in[20]; const float* beta= (const float*)d_in[21];
    const float* rmean=(const float*)d_in[22]; const float* rvar= (const float*)d_in[23];
    const float* Wc2 = (const float*)d_in[24]; const float* bc2 = (const float*)d_in[25];
    float* out = (float*)d_out;

    const int N = NN, E = EE, B = BB;

    char* w = (char*)d_ws;
    size_t off = 0;
    int* deg    = (int*)(w + off); off = al256(off + (size_t)N * 4);
    int* rowptr = (int*)(w + off); off = al256(off + (size_t)(N + 1) * 4);
    int* cursor = (int*)(w + off); off = al256(off + (size_t)N * 4);
    int* colarr = (int*)(w + off); off = al256(off + (size_t)E * 4);
    int* bsum   = (int*)(w + off); off = al256(off + 1024 * 4);
    float* h0   = (float*)(w + off); off = al256(off + (size_t)N * 8 * 4);
    float* SB   = (float*)(w + off); off = al256(off + (size_t)N * 128 * 4);
    ushort* XB1 = (ushort*)(w + off); off = al256(off + (size_t)N * 128 * 2);
    ushort* XB2 = (ushort*)(w + off); off = al256(off + (size_t)N * 128 * 2);
    float* pooled = (float*)(w + off); off = al256(off + (size_t)B * 128 * 4);
    // 8 split weight matrices in fragment layout: hi[8], lo[8], 16384 ushort each
    ushort* wfH[8]; ushort* wfL[8];
    for (int i = 0; i < 8; ++i) {
        wfH[i] = (ushort*)(w + off); off = al256(off + 16384 * 2);
        wfL[i] = (ushort*)(w + off); off = al256(off + 16384 * 2);
    }

    hipMemsetAsync(deg, 0, (size_t)N * 4, stream);
    hipMemsetAsync(pooled, 0, (size_t)B * 128 * 4, stream);

    // pre-split weights (order: W0b, W1a, W1b, W2a, W2b, Wjk0, Wjk1, Wjk2)
    const float* wsrc[8] = {W0b, W1a, W1b, W2a, W2b,
                            Wjk, Wjk + 128 * 128, Wjk + 256 * 128};
    for (int i = 0; i < 8; ++i)
        wsplit<<<64, 256, 0, stream>>>(wsrc[i], wfH[i], wfL[i]);

    int nb = (N + 1023) / 1024;   // 98

    count_deg<<<(E + 255) / 256, 256, 0, stream>>>(ei, deg, E);
    scan_partial<<<nb, 256, 0, stream>>>(deg, bsum, N);
    scan_bsum<<<1, 256, 0, stream>>>(bsum, nb);
    scan_apply<<<nb, 256, 0, stream>>>(deg, bsum, rowptr, cursor, N, E);
    fill_csr<<<(E + 255) / 256, 256, 0, stream>>>(ei, cursor, colarr, E);

    int gLin = (N + 63) / 64;   // 1563

    // Layer 0: agg(d=7) -> lin7 (= t0) -> fused [x1; jk0; pool], x1 -> XB1 (bf16)
    agg7<<<(N + 31) / 32, 256, 0, stream>>>(x, rowptr, colarr, h0, N);
    lin7<<<(N + 7) / 8, 256, 0, stream>>>(h0, W0a, b0a, SB, N);
    mlp_fused<false, false, false, true><<<gLin, 256, 0, stream>>>(
        SB, nullptr, rowptr, colarr,
        nullptr, nullptr, nullptr,
        wfH[0], wfL[0], b0b,
        wfH[5], wfL[5], nullptr,
        batch, XB1, pooled, N);

    // Layer 1: bf16 gather XB1 -> MLP -> x2 -> XB2 (bf16)
    mlp_fused<true, true, false, true><<<gLin, 256, 0, stream>>>(
        nullptr, XB1, rowptr, colarr,
        wfH[1], wfL[1], b1a,
        wfH[2], wfL[2], b1b,
        wfH[6], wfL[6], nullptr,
        batch, XB2, pooled, N);

    // Layer 2: bf16 gather XB2 -> MLP -> jk2 (x3 never materialized)
    mlp_fused<true, true, true, false><<<gLin, 256, 0, stream>>>(
        nullptr, XB2, rowptr, colarr,
        wfH[3], wfL[3], b2a,
        wfH[4], wfL[4], b2b,
        wfH[7], wfL[7], bjk,
        batch, nullptr, pooled, N);

    classifier<<<B, 256, 0, stream>>>(pooled, Wc1, bc1, gamma, beta,
                                      rmean, rvar, Wc2, bc2, out);
}